// Round 3
// baseline (178.275 us; speedup 1.0000x reference)
//
#include <hip/hip_runtime.h>

// EncoderLayer_36352603193491:
//   codes = census LBP of images [256,128,128] (zero-padded 3x3, 8 neighbors)
//   x = codes/127.5 - 1
//   thr = cumsum(normalized relu(lat)+1e-5) * 2 - 1   (8 thresholds)
//   out[b,h,w,t] = (x >= thr[t]) ? 1.0f : 0.0f        -> [256,128,128,8] f32
//
// R2 -> R3: same layout (one thread per 16B output chunk, fully-coalesced
// float4 stores), but store via clang ext_vector_type to satisfy
// __builtin_nontemporal_store's type requirements.

#define BN 256
#define HN 128
#define WN 128

typedef float float4v __attribute__((ext_vector_type(4)));

__global__ __launch_bounds__(256) void lbp_glt_kernel(
    const float* __restrict__ img,
    const float* __restrict__ lat,
    float* __restrict__ out)
{
    __shared__ int s_cmin[8];
    const int tid = threadIdx.x;

    if (tid < 8) {
        // Replicate reference float32 numerics exactly (no fma contraction).
        float pos[8];
        #pragma unroll
        for (int i = 0; i < 8; ++i) {
            float v = lat[i];
            v = v > 0.0f ? v : 0.0f;          // relu
            pos[i] = __fadd_rn(v, 1e-5f);
        }
        // numpy pairwise-sum order for n == 8: ((p0+p1)+(p2+p3)) + ((p4+p5)+(p6+p7))
        float total = __fadd_rn(
            __fadd_rn(__fadd_rn(pos[0], pos[1]), __fadd_rn(pos[2], pos[3])),
            __fadd_rn(__fadd_rn(pos[4], pos[5]), __fadd_rn(pos[6], pos[7])));
        // sequential cumsum of pos[i]/total up to this lane's index
        float cum = 0.0f;
        for (int i = 0; i <= tid; ++i)
            cum = __fadd_rn(cum, __fdiv_rn(pos[i], total));
        const float thr = __fsub_rn(__fmul_rn(cum, 2.0f), 1.0f);

        // smallest integer code c in [0,256] with (c*s - 1) >= thr
        const float s = (float)(1.0 / 127.5);  // matches np.float32(1.0/127.5)
        int g = (int)ceilf((thr + 1.0f) * 127.5f);
        if (g < 0) g = 0;
        if (g > 256) g = 256;
        while (g > 0) {
            float x = __fsub_rn(__fmul_rn((float)(g - 1), s), 1.0f);
            if (x >= thr) --g; else break;
        }
        while (g < 256) {
            float x = __fsub_rn(__fmul_rn((float)g, s), 1.0f);
            if (x < thr) ++g; else break;
        }
        s_cmin[tid] = g;
    }
    __syncthreads();

    // One thread per float4 output chunk: chunk c covers out[p][4*half .. 4*half+3]
    const long long c4 = (long long)blockIdx.x * 256 + tid;
    const int half = (int)(c4 & 1);
    const long long p = c4 >> 1;            // flat pixel index
    const int x = (int)(p & (WN - 1));
    const int y = (int)((p >> 7) & (HN - 1));
    const int b = (int)(p >> 14);

    const float* base = img + ((size_t)b << 14) + ((size_t)y << 7) + x;
    const float c = base[0];

    const bool ym = (y > 0), yp = (y < HN - 1);
    const bool xm = (x > 0), xp = (x < WN - 1);

    const float v_tl = (ym && xm) ? base[-WN - 1] : 0.0f;
    const float v_tc = ym         ? base[-WN]     : 0.0f;
    const float v_tr = (ym && xp) ? base[-WN + 1] : 0.0f;
    const float v_r  = xp         ? base[1]       : 0.0f;
    const float v_br = (yp && xp) ? base[WN + 1]  : 0.0f;
    const float v_bc = yp         ? base[WN]      : 0.0f;
    const float v_bl = (yp && xm) ? base[WN - 1]  : 0.0f;
    const float v_l  = xm         ? base[-1]      : 0.0f;

    const int code = (v_tl >= c ?   1 : 0)
                   | (v_tc >= c ?   2 : 0)
                   | (v_tr >= c ?   4 : 0)
                   | (v_r  >= c ?   8 : 0)
                   | (v_br >= c ?  16 : 0)
                   | (v_bc >= c ?  32 : 0)
                   | (v_bl >= c ?  64 : 0)
                   | (v_l  >= c ? 128 : 0);

    const int t0 = half * 4;
    float4v o;
    o.x = code >= s_cmin[t0 + 0] ? 1.0f : 0.0f;
    o.y = code >= s_cmin[t0 + 1] ? 1.0f : 0.0f;
    o.z = code >= s_cmin[t0 + 2] ? 1.0f : 0.0f;
    o.w = code >= s_cmin[t0 + 3] ? 1.0f : 0.0f;

    float4v* op = (float4v*)out + c4;
    __builtin_nontemporal_store(o, op);
}

extern "C" void kernel_launch(void* const* d_in, const int* in_sizes, int n_in,
                              void* d_out, int out_size, void* d_ws, size_t ws_size,
                              hipStream_t stream) {
    const float* img = (const float*)d_in[0];
    const float* lat = (const float*)d_in[1];
    float* out = (float*)d_out;

    const long long n_chunks = (long long)BN * HN * WN * 2;  // 8,388,608 float4s
    const int blocks = (int)(n_chunks / 256);                // 32,768
    lbp_glt_kernel<<<dim3(blocks), dim3(256), 0, stream>>>(img, lat, out);
}

// Round 4
// 153.892 us; speedup vs baseline: 1.1584x; 1.1584x over previous
//
#include <hip/hip_runtime.h>

// EncoderLayer_36352603193491:
//   codes = census LBP of images [256,128,128] (zero-padded 3x3, 8 neighbors)
//   x = codes/127.5 - 1
//   thr = cumsum(normalized relu(lat)+1e-5) * 2 - 1   (8 thresholds)
//   out[b,h,w,t] = (x >= thr[t]) ? 1.0f : 0.0f        -> [256,128,128,8] f32
//
// R3 -> R4: one thread per pixel (no duplicated stencil), fully-coalesced
// float4 stores achieved via two wave shuffles (lane i stores chunk base+i and
// base+64+i using code from lane i/2 resp. 32+i/2). Grid-stride persistent
// shape (2048 blocks, 8 pixels/thread) for outstanding-store depth. Regular
// stores (nt regressed in R3).

#define BN 256
#define HN 128
#define WN 128
#define NPIX (BN * HN * WN)       // 4,194,304
#define NBLOCKS 2048
#define NTHREADS (NBLOCKS * 256)  // 524,288 -> 8 pixels/thread

typedef float float4v __attribute__((ext_vector_type(4)));

__global__ __launch_bounds__(256) void lbp_glt_kernel(
    const float* __restrict__ img,
    const float* __restrict__ lat,
    float* __restrict__ out)
{
    __shared__ int s_cmin[8];
    const int tid = threadIdx.x;

    if (tid < 8) {
        // Replicate reference float32 numerics exactly (no fma contraction).
        float pos[8];
        #pragma unroll
        for (int i = 0; i < 8; ++i) {
            float v = lat[i];
            v = v > 0.0f ? v : 0.0f;          // relu
            pos[i] = __fadd_rn(v, 1e-5f);
        }
        // numpy pairwise-sum order for n == 8: ((p0+p1)+(p2+p3)) + ((p4+p5)+(p6+p7))
        float total = __fadd_rn(
            __fadd_rn(__fadd_rn(pos[0], pos[1]), __fadd_rn(pos[2], pos[3])),
            __fadd_rn(__fadd_rn(pos[4], pos[5]), __fadd_rn(pos[6], pos[7])));
        // sequential cumsum of pos[i]/total up to this lane's index
        float cum = 0.0f;
        for (int i = 0; i <= tid; ++i)
            cum = __fadd_rn(cum, __fdiv_rn(pos[i], total));
        const float thr = __fsub_rn(__fmul_rn(cum, 2.0f), 1.0f);

        // smallest integer code c in [0,256] with (c*s - 1) >= thr
        const float s = (float)(1.0 / 127.5);  // matches np.float32(1.0/127.5)
        int g = (int)ceilf((thr + 1.0f) * 127.5f);
        if (g < 0) g = 0;
        if (g > 256) g = 256;
        while (g > 0) {
            float x = __fsub_rn(__fmul_rn((float)(g - 1), s), 1.0f);
            if (x >= thr) --g; else break;
        }
        while (g < 256) {
            float x = __fsub_rn(__fmul_rn((float)g, s), 1.0f);
            if (x < thr) ++g; else break;
        }
        s_cmin[tid] = g;
    }
    __syncthreads();

    const int lane = tid & 63;
    // This lane always stores threshold group (lane&1): cutoffs in registers.
    const int h4 = (lane & 1) * 4;
    const int cm0 = s_cmin[h4 + 0];
    const int cm1 = s_cmin[h4 + 1];
    const int cm2 = s_cmin[h4 + 2];
    const int cm3 = s_cmin[h4 + 3];

    const int tg = blockIdx.x * 256 + tid;   // global thread id
    const int srcA = lane >> 1;              // shuffle sources (wave-relative)
    const int srcB = 32 + (lane >> 1);

    #pragma unroll 2
    for (int it = 0; it < NPIX / NTHREADS; ++it) {
        const int p = it * NTHREADS + tg;    // flat pixel index, < 2^22
        const int x = p & (WN - 1);
        const int y = (p >> 7) & (HN - 1);

        const float* base = img + (size_t)p;
        const float c = base[0];

        const bool ym = (y > 0), yp = (y < HN - 1);
        const bool xm = (x > 0), xp = (x < WN - 1);

        const float v_tl = (ym && xm) ? base[-WN - 1] : 0.0f;
        const float v_tc = ym         ? base[-WN]     : 0.0f;
        const float v_tr = (ym && xp) ? base[-WN + 1] : 0.0f;
        const float v_r  = xp         ? base[1]       : 0.0f;
        const float v_br = (yp && xp) ? base[WN + 1]  : 0.0f;
        const float v_bc = yp         ? base[WN]      : 0.0f;
        const float v_bl = (yp && xm) ? base[WN - 1]  : 0.0f;
        const float v_l  = xm         ? base[-1]      : 0.0f;

        const int code = (v_tl >= c ?   1 : 0)
                       | (v_tc >= c ?   2 : 0)
                       | (v_tr >= c ?   4 : 0)
                       | (v_r  >= c ?   8 : 0)
                       | (v_br >= c ?  16 : 0)
                       | (v_bc >= c ?  32 : 0)
                       | (v_bl >= c ?  64 : 0)
                       | (v_l  >= c ? 128 : 0);

        // Redistribute codes so the wave's 128 output chunks are stored
        // contiguously: chunk cbase+lane needs code of pixel pbase+(lane>>1),
        // chunk cbase+64+lane needs code of pixel pbase+32+(lane>>1).
        const int codeA = __shfl(code, srcA, 64);
        const int codeB = __shfl(code, srcB, 64);

        float4v oA, oB;
        oA.x = codeA >= cm0 ? 1.0f : 0.0f;
        oA.y = codeA >= cm1 ? 1.0f : 0.0f;
        oA.z = codeA >= cm2 ? 1.0f : 0.0f;
        oA.w = codeA >= cm3 ? 1.0f : 0.0f;
        oB.x = codeB >= cm0 ? 1.0f : 0.0f;
        oB.y = codeB >= cm1 ? 1.0f : 0.0f;
        oB.z = codeB >= cm2 ? 1.0f : 0.0f;
        oB.w = codeB >= cm3 ? 1.0f : 0.0f;

        const size_t cbase = 2 * (size_t)(p & ~63);   // wave's first chunk
        float4v* op = (float4v*)out + cbase;
        op[lane]      = oA;
        op[64 + lane] = oB;
    }
}

extern "C" void kernel_launch(void* const* d_in, const int* in_sizes, int n_in,
                              void* d_out, int out_size, void* d_ws, size_t ws_size,
                              hipStream_t stream) {
    const float* img = (const float*)d_in[0];
    const float* lat = (const float*)d_in[1];
    float* out = (float*)d_out;

    lbp_glt_kernel<<<dim3(NBLOCKS), dim3(256), 0, stream>>>(img, lat, out);
}